// Round 9
// baseline (325.576 us; speedup 1.0000x reference)
//
#include <hip/hip_runtime.h>
#include <cstdint>
#include <cstddef>

// SOM BMU: dists[b,m] = ||x[b] - W[:,m] + eps||, argmin/min over m.
//   sq = rowTerm[b] + colTerm[m] - 2*dot(x[b],W[:,m]) + D*eps^2
// dot via split-precision f16 MFMA (xh.wh + xh.wl + xl.wh, ~2^-22 rel err).
// R9: double-buffered GLDS pipeline, ONE barrier per K-step placed so the
// vmcnt(0) drain hits loads aged by a full 48-MFMA compute phase (~930+
// SIMD-cyc > HBM latency). 128x128 tile, BK=32, 2x32KB LDS buffers.
// Storage pre-swizzled by prep: addr16(r,c) = (r>>4)*32768 + (c>>2)*1024 +
// (c&3)*256 + (r&15)*16 -> GLDS staging is linear lane-order (coalesced
// 1KB/wave) and fragment ds_read_b128 is conflict-free (R8-verified).
// XCD swizzle: all 16 row-blocks of a col-tile land on one XCD's L2.
// Argmin via packed u64 key (dist_bits<<32 | m) + atomicMin.

#define B_  2048
#define D_  1024
#define M_  16384
#define EPS_ 1e-6f

typedef _Float16 v8h __attribute__((ext_vector_type(8)));
typedef float    v4f __attribute__((ext_vector_type(4)));

static __device__ __forceinline__ unsigned long long umin64(unsigned long long a,
                                                            unsigned long long b) {
    return a < b ? a : b;
}

// swizzled 16B-chunk byte address: row r, k-chunk c (8 f16 per chunk)
static __device__ __forceinline__ size_t addr16(int r, int c) {
    return (size_t)(r >> 4) * 32768 + (size_t)(c >> 2) * 1024 +
           (size_t)(c & 3) * 256 + (size_t)(r & 15) * 16;
}

#define GLDS16(g, l)                                                            \
    __builtin_amdgcn_global_load_lds(                                           \
        (const __attribute__((address_space(1))) void*)(g),                     \
        (__attribute__((address_space(3))) void*)(l), 16, 0, 0)

// ---------- fused prep ----------
// blocks 0..4095: W 64x64 tiles (transpose+split+colTerm partials)
// blocks 4096..4351: x, 8 rows each (split+rowTerm)
// block 4352: keys + loss-slot init.  colTerm must be memset(0) first.
__global__ __launch_bounds__(256) void prep(
    const float* __restrict__ x, const float* __restrict__ W,
    _Float16* __restrict__ xh, _Float16* __restrict__ xl,
    _Float16* __restrict__ wth, _Float16* __restrict__ wtl,
    float* __restrict__ rowTerm, float* __restrict__ colTerm,
    unsigned long long* __restrict__ keys, float* __restrict__ out)
{
    const int t = threadIdx.x;
    const int blk = blockIdx.x;
    if (blk < 4096) {
        __shared__ float tile[64][65];
        const int m0 = (blk & 255) * 64;
        const int d0 = (blk >> 8) * 64;
        const int dloc = t >> 4, mq = (t & 15) * 4;
        #pragma unroll
        for (int s = 0; s < 4; ++s) {
            float4 v = *(const float4*)(W + (size_t)(d0 + dloc + 16 * s) * M_ + m0 + mq);
            tile[dloc + 16 * s][mq + 0] = v.x;
            tile[dloc + 16 * s][mq + 1] = v.y;
            tile[dloc + 16 * s][mq + 2] = v.z;
            tile[dloc + 16 * s][mq + 3] = v.w;
        }
        __syncthreads();
        const int mloc = t >> 2, j = t & 3;
        const int dc = j * 16;
        v8h h0, l0, h1, l1;
        float part = 0.f;
        #pragma unroll
        for (int e = 0; e < 8; ++e) {
            float v = tile[dc + e][mloc];
            _Float16 hi = (_Float16)v;
            h0[e] = hi; l0[e] = (_Float16)(v - (float)hi);
            part += v * v - 2.0f * EPS_ * v;
        }
        #pragma unroll
        for (int e = 0; e < 8; ++e) {
            float v = tile[dc + 8 + e][mloc];
            _Float16 hi = (_Float16)v;
            h1[e] = hi; l1[e] = (_Float16)(v - (float)hi);
            part += v * v - 2.0f * EPS_ * v;
        }
        const int m  = m0 + mloc;
        const int c0 = (d0 >> 3) + j * 2;
        const size_t a0 = addr16(m, c0), a1 = addr16(m, c0 + 1);
        *(v8h*)((char*)wth + a0) = h0; *(v8h*)((char*)wth + a1) = h1;
        *(v8h*)((char*)wtl + a0) = l0; *(v8h*)((char*)wtl + a1) = l1;
        part += __shfl_xor(part, 1, 64);
        part += __shfl_xor(part, 2, 64);
        if (j == 0) atomicAdd(&colTerm[m], part);
    } else if (blk < 4352) {
        __shared__ float rsum[2];
        const int rb0 = (blk - 4096) * 8;
        for (int p = 0; p < 4; ++p) {
            if (t < 2) rsum[t] = 0.f;
            __syncthreads();
            const int r = rb0 + 2 * p + (t >> 7);
            const int c = t & 127;
            float4 q1 = *(const float4*)(x + (size_t)r * D_ + 8 * c);
            float4 q2 = *(const float4*)(x + (size_t)r * D_ + 8 * c + 4);
            float vv[8] = {q1.x, q1.y, q1.z, q1.w, q2.x, q2.y, q2.z, q2.w};
            v8h h, l;
            float part = 0.f;
            #pragma unroll
            for (int e = 0; e < 8; ++e) {
                _Float16 hi = (_Float16)vv[e];
                h[e] = hi; l[e] = (_Float16)(vv[e] - (float)hi);
                part += vv[e] * vv[e] + 2.0f * EPS_ * vv[e];
            }
            const size_t a = addr16(r, c);
            *(v8h*)((char*)xh + a) = h;
            *(v8h*)((char*)xl + a) = l;
            for (int off = 32; off; off >>= 1) part += __shfl_down(part, off, 64);
            if ((t & 63) == 0) atomicAdd(&rsum[t >> 7], part);
            __syncthreads();
            if ((t & 127) == 0) rowTerm[r] = rsum[t >> 7];
            __syncthreads();
        }
    } else {
        for (int i = t; i < B_; i += 256) keys[i] = ~0ull;
        if (t == 0) out[3 * B_] = 0.f;
    }
}

// ---------- main MFMA distance GEMM + argmin ----------
// 128x128 tile, 4 waves (2x2 of 64x64), BK=32, 16x16x32 f16 MFMA.
__global__ __launch_bounds__(256, 2) void som_mfma(
    const _Float16* __restrict__ xh, const _Float16* __restrict__ xl,
    const _Float16* __restrict__ wth, const _Float16* __restrict__ wtl,
    const float* __restrict__ rowTerm, const float* __restrict__ colTerm,
    unsigned long long* __restrict__ keys)
{
    __shared__ __align__(16) char smem[65536];  // 2 x 32KB: Ah|Al|Bh|Bl (8KB ea)

    const int t = threadIdx.x;
    const int g = blockIdx.x;
    // XCD swizzle: 16 row-blocks of one col-tile share g&7 (same XCD)
    const int colTile = (g & 7) | ((g >> 7) << 3);
    const int rowTile = (g >> 3) & 15;
    const int cb = colTile * 128, rb = rowTile * 128;

    const int L = t & 63, w = t >> 6;
    const int wro = (w >> 1) * 64, wco = (w & 1) * 64;
    const int c16 = L & 15, kq = L >> 4;

    // staging sources: per call, wave wgrp covers one 16-row group (1KB linear)
    const size_t sa0 = (size_t)((rb >> 4) + (t >> 6)) * 32768 + (t & 63) * 16;
    const size_t sa1 = sa0 + 4ull * 32768;
    const size_t sb0 = (size_t)((cb >> 4) + (t >> 6)) * 32768 + (t & 63) * 16;
    const size_t sb1 = sb0 + 4ull * 32768;
    const int ldsw = (t & 192) * 16;   // wave-uniform; HW adds lane*16

    const char* pxh = (const char*)xh;
    const char* pxl = (const char*)xl;
    const char* pwh = (const char*)wth;
    const char* pwl = (const char*)wtl;

    v4f acc[4][4];
    #pragma unroll
    for (int i = 0; i < 4; ++i)
        #pragma unroll
        for (int j = 0; j < 4; ++j) acc[i][j] = (v4f){0.f, 0.f, 0.f, 0.f};

    // fragment offsets (f16 units) within an 8KB region
    const int lofs = kq * 128 + c16 * 8;
    int ia[4], ib[4];
    #pragma unroll
    for (int i = 0; i < 4; ++i) ia[i] = ((wro >> 4) + i) * 512 + lofs;
    #pragma unroll
    for (int j = 0; j < 4; ++j) ib[j] = ((wco >> 4) + j) * 512 + lofs;

    #define STAGE(off, S)                                                       \
        do {                                                                    \
            const size_t ko = (size_t)(S) * 1024;                               \
            GLDS16(pxh + sa0 + ko, smem + (off) + ldsw);                        \
            GLDS16(pxh + sa1 + ko, smem + (off) + 4096 + ldsw);                 \
            GLDS16(pxl + sa0 + ko, smem + (off) + 8192 + ldsw);                 \
            GLDS16(pxl + sa1 + ko, smem + (off) + 12288 + ldsw);                \
            GLDS16(pwh + sb0 + ko, smem + (off) + 16384 + ldsw);                \
            GLDS16(pwh + sb1 + ko, smem + (off) + 20480 + ldsw);                \
            GLDS16(pwl + sb0 + ko, smem + (off) + 24576 + ldsw);                \
            GLDS16(pwl + sb1 + ko, smem + (off) + 28672 + ldsw);                \
        } while (0)

    #define FRAGS(off)                                                          \
        do {                                                                    \
            const _Float16* ba = (const _Float16*)(smem + (off));               \
            _Pragma("unroll")                                                   \
            for (int i = 0; i < 4; ++i) {                                       \
                ah[i] = *(const v8h*)(ba + ia[i]);                              \
                al[i] = *(const v8h*)(ba + 4096 + ia[i]);                       \
            }                                                                   \
            _Pragma("unroll")                                                   \
            for (int j = 0; j < 4; ++j) {                                       \
                bh[j] = *(const v8h*)(ba + 8192 + ib[j]);                       \
                bl[j] = *(const v8h*)(ba + 12288 + ib[j]);                      \
            }                                                                   \
        } while (0)

    #define MFMAS                                                               \
        do {                                                                    \
            _Pragma("unroll")                                                   \
            for (int i = 0; i < 4; ++i)                                         \
                _Pragma("unroll")                                               \
                for (int j = 0; j < 4; ++j)                                     \
                    acc[i][j] = __builtin_amdgcn_mfma_f32_16x16x32_f16(         \
                        ah[i], bh[j], acc[i][j], 0, 0, 0);                      \
            _Pragma("unroll")                                                   \
            for (int i = 0; i < 4; ++i)                                         \
                _Pragma("unroll")                                               \
                for (int j = 0; j < 4; ++j)                                     \
                    acc[i][j] = __builtin_amdgcn_mfma_f32_16x16x32_f16(         \
                        ah[i], bl[j], acc[i][j], 0, 0, 0);                      \
            _Pragma("unroll")                                                   \
            for (int i = 0; i < 4; ++i)                                         \
                _Pragma("unroll")                                               \
                for (int j = 0; j < 4; ++j)                                     \
                    acc[i][j] = __builtin_amdgcn_mfma_f32_16x16x32_f16(         \
                        al[i], bh[j], acc[i][j], 0, 0, 0);                      \
        } while (0)

    v8h ah[4], al[4], bh[4], bl[4];

    STAGE(0, 0);                       // tile 0 (drain un-aged, once)

    for (int p = 0; p < 16; ++p) {
        __syncthreads();               // drains tile-2p loads (aged 1 phase)
        FRAGS(0);
        STAGE(32768, 2 * p + 1);       // tile 2p+1 -> buf1
        MFMAS;
        __syncthreads();               // drains tile-(2p+1) loads (aged)
        FRAGS(32768);
        if (p != 15) STAGE(0, 2 * p + 2);  // tile 2p+2 -> buf0
        MFMAS;
    }

    #undef STAGE
    #undef FRAGS
    #undef MFMAS

    // epilogue: C/D layout col=lane&15, row=(lane>>4)*4+reg  [verified m89/m91]
    float cT[4];
    #pragma unroll
    for (int j = 0; j < 4; ++j) cT[j] = colTerm[cb + wco + j * 16 + c16];
    const float de2 = (float)D_ * EPS_ * EPS_;
    #pragma unroll
    for (int i = 0; i < 4; ++i) {
        #pragma unroll
        for (int r = 0; r < 4; ++r) {
            int row_g = rb + wro + i * 16 + kq * 4 + r;
            float rt = rowTerm[row_g];
            unsigned long long best = ~0ull;
            #pragma unroll
            for (int j = 0; j < 4; ++j) {
                float sq = rt + cT[j] - 2.0f * acc[i][j][r] + de2;
                sq = fmaxf(sq, 0.0f);
                float dist = sqrtf(sq);
                unsigned long long key =
                    ((unsigned long long)__float_as_uint(dist) << 32) |
                    (unsigned int)(cb + wco + j * 16 + c16);
                best = umin64(best, key);
            }
            #pragma unroll
            for (int m = 1; m <= 8; m <<= 1) {
                unsigned long long o =
                    (unsigned long long)__shfl_xor((long long)best, m, 64);
                best = umin64(best, o);
            }
            if (c16 == 0) atomicMin(&keys[row_g], best);
        }
    }
}

// ---------- fallback fp32 path (used only if ws too small) ----------
__global__ void row_stats(const float* __restrict__ x, float* __restrict__ rowTerm) {
    int b = blockIdx.x;
    const float* xr = x + (size_t)b * D_;
    int t = threadIdx.x;
    float acc = 0.f;
    for (int i = t; i < D_; i += 256) {
        float v = xr[i];
        acc += v * v + 2.0f * EPS_ * v;
    }
    for (int off = 32; off; off >>= 1) acc += __shfl_down(acc, off, 64);
    __shared__ float s[4];
    if ((t & 63) == 0) s[t >> 6] = acc;
    __syncthreads();
    if (t == 0) rowTerm[b] = s[0] + s[1] + s[2] + s[3];
}

__global__ void col_stats(const float* __restrict__ w, float* __restrict__ colTerm) {
    int m = blockIdx.x * 256 + threadIdx.x;
    int d0 = blockIdx.y * 64;
    const float* p = w + (size_t)d0 * M_ + m;
    float acc = 0.f;
    #pragma unroll 8
    for (int d = 0; d < 64; ++d) {
        float v = p[(size_t)d * M_];
        acc += v * v - 2.0f * EPS_ * v;
    }
    atomicAdd(&colTerm[m], acc);
}

__global__ __launch_bounds__(256, 2) void som_gemm(
    const float* __restrict__ A, const float* __restrict__ Wt,
    const float* __restrict__ rowTerm, const float* __restrict__ colTerm,
    unsigned long long* __restrict__ keys)
{
    __shared__ float As[8][128];
    __shared__ float Bs[8][128];
    const int t  = threadIdx.x;
    const int rb = blockIdx.y * 128;
    const int cb = blockIdx.x * 128;
    const int tx = t & 15;
    const int ty = t >> 4;
    float acc[8][8];
    #pragma unroll
    for (int i = 0; i < 8; ++i)
        #pragma unroll
        for (int j = 0; j < 8; ++j) acc[i][j] = 0.f;
    const int la_row = t >> 1, la_k = (t & 1) * 4;
    const int lb_k = t >> 5, lb_n = (t & 31) * 4;
    const float* Aptr = A + (size_t)(rb + la_row) * D_ + la_k;
    const float* Bptr = Wt + (size_t)lb_k * M_ + cb + lb_n;
    for (int k0 = 0; k0 < D_; k0 += 8) {
        float4 av = *(const float4*)(Aptr + k0);
        float4 bv = *(const float4*)(Bptr + (size_t)k0 * M_);
        __syncthreads();
        As[la_k + 0][la_row] = av.x;
        As[la_k + 1][la_row] = av.y;
        As[la_k + 2][la_row] = av.z;
        As[la_k + 3][la_row] = av.w;
        *(float4*)&Bs[lb_k][lb_n] = bv;
        __syncthreads();
        #pragma unroll
        for (int k = 0; k < 8; ++k) {
            float a[8], b[8];
            #pragma unroll
            for (int i = 0; i < 8; ++i) a[i] = As[k][ty * 8 + i];
            #pragma unroll
            for (int j = 0; j < 8; ++j) b[j] = Bs[k][tx * 8 + j];
            #pragma unroll
            for (int i = 0; i < 8; ++i)
                #pragma unroll
                for (int j = 0; j < 8; ++j) acc[i][j] += a[i] * b[j];
        }
    }
    float rT[8], cT[8];
    #pragma unroll
    for (int i = 0; i < 8; ++i) rT[i] = rowTerm[rb + ty * 8 + i];
    #pragma unroll
    for (int j = 0; j < 8; ++j) cT[j] = colTerm[cb + tx * 8 + j];
    const float de2 = (float)D_ * EPS_ * EPS_;
    #pragma unroll
    for (int i = 0; i < 8; ++i) {
        unsigned long long best = ~0ull;
        #pragma unroll
        for (int j = 0; j < 8; ++j) {
            float sq = rT[i] + cT[j] - 2.0f * acc[i][j] + de2;
            sq = fmaxf(sq, 0.0f);
            float dist = sqrtf(sq);
            unsigned long long key =
                ((unsigned long long)__float_as_uint(dist) << 32) |
                (unsigned int)(cb + tx * 8 + j);
            best = umin64(best, key);
        }
        #pragma unroll
        for (int msk = 1; msk <= 8; msk <<= 1) {
            unsigned long long o = __shfl_xor((long long)best, msk, 64);
            best = umin64(best, (unsigned long long)o);
        }
        if (tx == 0) atomicMin(&keys[rb + ty * 8 + i], best);
    }
}

// ---------- finalize: 8 blocks of 256 rows ----------
__global__ void finalize(const unsigned long long* __restrict__ keys,
                         const float* __restrict__ loc,
                         float* __restrict__ out)
{
    int t = threadIdx.x;
    int r = blockIdx.x * 256 + t;
    unsigned long long k = keys[r];
    unsigned int idx = (unsigned int)(k & 0xFFFFFFFFu);
    float dist = __uint_as_float((unsigned int)(k >> 32));
    out[r] = (float)idx;
    out[B_ + 2 * r]     = loc[2 * idx];
    out[B_ + 2 * r + 1] = loc[2 * idx + 1];
    float sum = dist;
    for (int off = 32; off; off >>= 1) sum += __shfl_down(sum, off, 64);
    __shared__ float s[4];
    if ((t & 63) == 0) s[t >> 6] = sum;
    __syncthreads();
    if (t == 0) atomicAdd(&out[3 * B_], (s[0] + s[1] + s[2] + s[3]) / (float)B_);
}

extern "C" void kernel_launch(void* const* d_in, const int* in_sizes, int n_in,
                              void* d_out, int out_size, void* d_ws, size_t ws_size,
                              hipStream_t stream)
{
    const float* x   = (const float*)d_in[0];
    const float* w   = (const float*)d_in[1];
    const float* loc = (const float*)d_in[2];
    float* out = (float*)d_out;

    char* ws = (char*)d_ws;
    unsigned long long* keys = (unsigned long long*)ws;   // 16 KB
    float* rowTerm = (float*)(ws + (16 << 10));           //  8 KB
    float* colTerm = (float*)(ws + (24 << 10));           // 64 KB
    _Float16* xh  = (_Float16*)(ws + (1ull << 20));       //  4 MB
    _Float16* xl  = (_Float16*)(ws + (5ull << 20));       //  4 MB
    _Float16* wth = (_Float16*)(ws + (9ull << 20));       // 32 MB
    _Float16* wtl = (_Float16*)(ws + (41ull << 20));      // 32 MB
    const size_t NEED = 73ull << 20;

    if (ws_size >= NEED) {
        hipMemsetAsync(colTerm, 0, M_ * sizeof(float), stream);
        prep<<<4353, 256, 0, stream>>>(x, w, xh, xl, wth, wtl,
                                       rowTerm, colTerm, keys, out);
        som_mfma<<<2048, 256, 0, stream>>>(
            xh, xl, wth, wtl, rowTerm, colTerm, keys);
    } else {
        hipMemsetAsync(keys, 0xFF, B_ * sizeof(unsigned long long), stream);
        hipMemsetAsync(colTerm, 0, M_ * sizeof(float), stream);
        hipMemsetAsync(out + 3 * B_, 0, sizeof(float), stream);
        row_stats<<<B_, 256, 0, stream>>>(x, rowTerm);
        col_stats<<<dim3(M_ / 256, D_ / 64), 256, 0, stream>>>(w, colTerm);
        som_gemm<<<dim3(M_ / 128, B_ / 128), 256, 0, stream>>>(
            x, w, rowTerm, colTerm, keys);
    }
    finalize<<<8, 256, 0, stream>>>(keys, loc, out);
}